// Round 1
// baseline (1984.991 us; speedup 1.0000x reference)
//
#include <hip/hip_runtime.h>

#define N_IN   262144
#define N_OUT  262144
#define KOFF   27
#define MPAIR  131072
#define C      64
#define EPS    1e-5f
#define NEG_SLOPE 0.01f

// ---- bucketed-merge parameters -------------------------------------------
#define BROWS   64                    // output rows per bucket (16 KB fp32 tile)
#define NBUCKET (N_OUT / BROWS)       // 4096
#define NKEY    (NBUCKET * KOFF)      // 110592 (bucket-major, k minor)
#define SLOTS   96                    // per-key capacity; lambda=32, P(ovfl)~1e-18

// ---------------------------------------------------------------------------
// Phase 1: bin every (k, pair) into its (out-bucket, k) key.
// record = im (18b) | (om & 63) << 18   -- fits one dword.
// ---------------------------------------------------------------------------
__global__ __launch_bounds__(256) void scatter_kernel(
    const int* __restrict__ in_map,
    const int* __restrict__ out_map,
    int*       __restrict__ cnt,
    unsigned int* __restrict__ recs)
{
    const int k = blockIdx.y;
    const int m = blockIdx.x * 256 + threadIdx.x;
    const size_t p = (size_t)k * MPAIR + m;
    const int om = out_map[p];
    const int im = in_map[p];
    const int key = (om >> 6) * KOFF + k;
    const int pos = atomicAdd(&cnt[key], 1);
    if (pos < SLOTS)
        recs[(size_t)key * SLOTS + pos] =
            (unsigned int)im | ((unsigned int)(om & 63) << 18);
}

// ---------------------------------------------------------------------------
// Phase 2: one block per bucket of 64 output rows. Waves stripe over k so
// W[k][:,lane] stays register-resident across a k-group (~32 records).
// Contributions merge in an LDS tile (ds_add_f32); out written ONCE,
// no global atomics. Per-channel stats fused from the tile.
// ---------------------------------------------------------------------------
__global__ __launch_bounds__(256) void conv_merge_kernel(
    const float* __restrict__ feats,
    const float* __restrict__ W,
    const int*   __restrict__ cnt,
    const unsigned int* __restrict__ recs,
    float*       __restrict__ out,
    float*       __restrict__ stats)
{
    const int bucket = blockIdx.x;
    const int lane = threadIdx.x & 63;
    const int wave = threadIdx.x >> 6;

    __shared__ __align__(16) float tile[BROWS * C];   // 16 KB accumulator
    __shared__ __align__(16) float ring[4][2][C];     // per-wave broadcast ring
    __shared__ float4 s_sum[256], s_sq[256];          // stats reduce (8 KB)

    #pragma unroll
    for (int i = threadIdx.x; i < BROWS * C; i += 256) tile[i] = 0.f;
    __syncthreads();

    for (int k = wave; k < KOFF; k += 4) {
        const int key = bucket * KOFF + k;
        int n = cnt[key];
        n = __builtin_amdgcn_readfirstlane(n > SLOTS ? SLOTS : n);
        if (n == 0) continue;
        const unsigned int* rbase = recs + (size_t)key * SLOTS;

        // register-resident weight column: wreg[i] = W[k][i][lane]
        float wreg[C];
        const float* Wk = W + (size_t)k * C * C;
        #pragma unroll
        for (int i = 0; i < C; ++i) wreg[i] = Wk[i * C + lane];

        unsigned int rec = rbase[0];
        int im = __builtin_amdgcn_readfirstlane((int)(rec & 0x3FFFFu));
        float f = feats[(size_t)im * C + lane];

        for (int r = 0; r < n; ++r) {
            const int row = __builtin_amdgcn_readfirstlane((int)(rec >> 18));
            const int buf = r & 1;
            ring[wave][buf][lane] = f;

            if (r + 1 < n) {                      // prefetch next row
                rec = rbase[r + 1];
                int imn = __builtin_amdgcn_readfirstlane((int)(rec & 0x3FFFFu));
                f = feats[(size_t)imn * C + lane]; // overlaps compute below
            }

            float acc = 0.f;
            #pragma unroll
            for (int j = 0; j < 16; ++j) {
                const float4 v = *(const float4*)&ring[wave][buf][4 * j];
                acc = fmaf(v.x, wreg[4*j+0], acc);
                acc = fmaf(v.y, wreg[4*j+1], acc);
                acc = fmaf(v.z, wreg[4*j+2], acc);
                acc = fmaf(v.w, wreg[4*j+3], acc);
            }
            atomicAdd(&tile[row * C + lane], acc);   // ds_add_f32, bank-rate
        }
    }
    __syncthreads();

    // Coalesced tile -> out store, with fused per-channel sum / sumsq.
    const int col4 = threadIdx.x & 15;   // channels 4*col4 .. +3
    const int rowg = threadIdx.x >> 4;   // rows rowg, rowg+16, rowg+32, rowg+48
    float4 s = make_float4(0.f, 0.f, 0.f, 0.f);
    float4 q = make_float4(0.f, 0.f, 0.f, 0.f);
    #pragma unroll
    for (int j = 0; j < 4; ++j) {
        const int row = rowg + j * 16;
        float4 v = *(const float4*)&tile[row * C + col4 * 4];
        *(float4*)&out[(size_t)bucket * (BROWS * C) + row * C + col4 * 4] = v;
        s.x += v.x; s.y += v.y; s.z += v.z; s.w += v.w;
        q.x = fmaf(v.x, v.x, q.x); q.y = fmaf(v.y, v.y, q.y);
        q.z = fmaf(v.z, v.z, q.z); q.w = fmaf(v.w, v.w, q.w);
    }
    s_sum[threadIdx.x] = s; s_sq[threadIdx.x] = q;
    __syncthreads();

    if (threadIdx.x < 16) {
        float4 ts = make_float4(0.f, 0.f, 0.f, 0.f);
        float4 tq = make_float4(0.f, 0.f, 0.f, 0.f);
        for (int j = 0; j < 16; ++j) {
            float4 a = s_sum[j * 16 + threadIdx.x];
            float4 b = s_sq [j * 16 + threadIdx.x];
            ts.x += a.x; ts.y += a.y; ts.z += a.z; ts.w += a.w;
            tq.x += b.x; tq.y += b.y; tq.z += b.z; tq.w += b.w;
        }
        const int c0 = threadIdx.x * 4;
        unsafeAtomicAdd(&stats[c0 + 0], ts.x);
        unsafeAtomicAdd(&stats[c0 + 1], ts.y);
        unsafeAtomicAdd(&stats[c0 + 2], ts.z);
        unsafeAtomicAdd(&stats[c0 + 3], ts.w);
        unsafeAtomicAdd(&stats[64 + c0 + 0], tq.x);
        unsafeAtomicAdd(&stats[64 + c0 + 1], tq.y);
        unsafeAtomicAdd(&stats[64 + c0 + 2], tq.z);
        unsafeAtomicAdd(&stats[64 + c0 + 3], tq.w);
    }
}

// ---------------------------------------------------------------------------
// LEGACY PATH (fallback if workspace too small): verified previous kernels.
// ---------------------------------------------------------------------------
__global__ __launch_bounds__(256) void conv_kernel(
    const float* __restrict__ feats,
    const float* __restrict__ W,
    const int*   __restrict__ in_map,
    const int*   __restrict__ out_map,
    float*       __restrict__ out)
{
    const int k    = blockIdx.y;
    const int lane = threadIdx.x & 63;
    const int wave = threadIdx.x >> 6;

    __shared__ float4 fr4[4][2][16];

    float wreg[C];
    const float* Wk = W + (size_t)k * C * C;
    #pragma unroll
    for (int i = 0; i < C; ++i) wreg[i] = Wk[i * C + lane];

    const int pair_base = (blockIdx.x * 4 + wave) * 64;
    const int my_pair   = pair_base + lane;
    const int my_im = in_map[(size_t)k * MPAIR + my_pair];
    const int my_om = out_map[(size_t)k * MPAIR + my_pair];

    int im0 = __builtin_amdgcn_readlane(my_im, 0);
    float fcur = feats[(size_t)im0 * C + lane];

    for (int p = 0; p < 64; ++p) {
        const int om  = __builtin_amdgcn_readlane(my_om, p);
        const int buf = p & 1;

        ((float*)&fr4[wave][buf][0])[lane] = fcur;

        if (p < 63) {
            int imn = __builtin_amdgcn_readlane(my_im, p + 1);
            fcur = feats[(size_t)imn * C + lane];
        }

        float acc = 0.f;
        #pragma unroll
        for (int j = 0; j < 16; ++j) {
            float4 f = fr4[wave][buf][j];
            acc = fmaf(f.x, wreg[4*j+0], acc);
            acc = fmaf(f.y, wreg[4*j+1], acc);
            acc = fmaf(f.z, wreg[4*j+2], acc);
            acc = fmaf(f.w, wreg[4*j+3], acc);
        }
        unsafeAtomicAdd(&out[(size_t)om * C + lane], acc);
    }
}

__global__ __launch_bounds__(256) void stats_kernel(
    const float* __restrict__ out, float* __restrict__ stats)
{
    __shared__ float4 s_sum[256], s_sq[256];
    const int col4 = threadIdx.x & 15;
    const int rowg = threadIdx.x >> 4;

    float4 s = make_float4(0.f, 0.f, 0.f, 0.f);
    float4 q = make_float4(0.f, 0.f, 0.f, 0.f);
    for (int row = blockIdx.x * 16 + rowg; row < N_OUT; row += gridDim.x * 16) {
        float4 v = *(const float4*)(out + (size_t)row * C + col4 * 4);
        s.x += v.x; s.y += v.y; s.z += v.z; s.w += v.w;
        q.x = fmaf(v.x, v.x, q.x); q.y = fmaf(v.y, v.y, q.y);
        q.z = fmaf(v.z, v.z, q.z); q.w = fmaf(v.w, v.w, q.w);
    }
    s_sum[threadIdx.x] = s; s_sq[threadIdx.x] = q;
    __syncthreads();

    if (threadIdx.x < 16) {
        float4 ts = make_float4(0.f, 0.f, 0.f, 0.f);
        float4 tq = make_float4(0.f, 0.f, 0.f, 0.f);
        for (int j = 0; j < 16; ++j) {
            float4 a = s_sum[j * 16 + threadIdx.x];
            float4 b = s_sq [j * 16 + threadIdx.x];
            ts.x += a.x; ts.y += a.y; ts.z += a.z; ts.w += a.w;
            tq.x += b.x; tq.y += b.y; tq.z += b.z; tq.w += b.w;
        }
        const int c0 = threadIdx.x * 4;
        unsafeAtomicAdd(&stats[c0 + 0], ts.x);
        unsafeAtomicAdd(&stats[c0 + 1], ts.y);
        unsafeAtomicAdd(&stats[c0 + 2], ts.z);
        unsafeAtomicAdd(&stats[c0 + 3], ts.w);
        unsafeAtomicAdd(&stats[64 + c0 + 0], tq.x);
        unsafeAtomicAdd(&stats[64 + c0 + 1], tq.y);
        unsafeAtomicAdd(&stats[64 + c0 + 2], tq.z);
        unsafeAtomicAdd(&stats[64 + c0 + 3], tq.w);
    }
}

// ---------------------------------------------------------------------------
// In-place BN (affine) + LeakyReLU (shared by both paths).
// ---------------------------------------------------------------------------
__global__ __launch_bounds__(256) void bn_kernel(
    float* __restrict__ out,
    const float* __restrict__ stats,
    const float* __restrict__ gamma,
    const float* __restrict__ beta)
{
    __shared__ __align__(16) float s_scale[C];
    __shared__ __align__(16) float s_shift[C];
    if (threadIdx.x < C) {
        const float inv_n = 1.0f / (float)N_OUT;
        float mean = stats[threadIdx.x] * inv_n;
        float var  = stats[C + threadIdx.x] * inv_n - mean * mean;
        float sc   = gamma[threadIdx.x] * rsqrtf(var + EPS);
        s_scale[threadIdx.x] = sc;
        s_shift[threadIdx.x] = beta[threadIdx.x] - mean * sc;
    }
    __syncthreads();

    const int col4 = threadIdx.x & 15;
    const int rowg = threadIdx.x >> 4;
    const float4 sc4 = *(const float4*)&s_scale[col4 * 4];
    const float4 sh4 = *(const float4*)&s_shift[col4 * 4];

    for (int row = blockIdx.x * 16 + rowg; row < N_OUT; row += gridDim.x * 16) {
        float4* p = (float4*)(out + (size_t)row * C + col4 * 4);
        float4 v = *p;
        v.x = fmaf(v.x, sc4.x, sh4.x);
        v.y = fmaf(v.y, sc4.y, sh4.y);
        v.z = fmaf(v.z, sc4.z, sh4.z);
        v.w = fmaf(v.w, sc4.w, sh4.w);
        v.x = v.x >= 0.f ? v.x : NEG_SLOPE * v.x;
        v.y = v.y >= 0.f ? v.y : NEG_SLOPE * v.y;
        v.z = v.z >= 0.f ? v.z : NEG_SLOPE * v.z;
        v.w = v.w >= 0.f ? v.w : NEG_SLOPE * v.w;
        *p = v;
    }
}

extern "C" void kernel_launch(void* const* d_in, const int* in_sizes, int n_in,
                              void* d_out, int out_size, void* d_ws, size_t ws_size,
                              hipStream_t stream) {
    const float* feats  = (const float*)d_in[0];
    const float* W      = (const float*)d_in[1];
    const float* gamma  = (const float*)d_in[2];
    const float* beta   = (const float*)d_in[3];
    const int*  in_map  = (const int*)d_in[4];
    const int*  out_map = (const int*)d_in[5];
    // d_in[6] = num_out (known constant N_OUT)

    float* out   = (float*)d_out;
    float* stats = (float*)d_ws;                       // 128 floats @ offset 0

    const size_t CNT_OFF = 1024;
    const size_t REC_OFF = CNT_OFF + (size_t)NKEY * 4;             // 443,392
    const size_t NEEDED  = REC_OFF + (size_t)NKEY * SLOTS * 4;     // ~41 MB

    if (ws_size >= NEEDED) {
        // --- bucketed-merge path: no global fp atomics, out written once ---
        int* cnt = (int*)((char*)d_ws + CNT_OFF);
        unsigned int* recs = (unsigned int*)((char*)d_ws + REC_OFF);

        hipMemsetAsync(stats, 0, 2 * C * sizeof(float), stream);
        hipMemsetAsync(cnt, 0, (size_t)NKEY * sizeof(int), stream);
        // NOTE: no memset of out -- conv_merge fully overwrites every row.

        dim3 sgrid(MPAIR / 256, KOFF);
        scatter_kernel<<<sgrid, 256, 0, stream>>>(in_map, out_map, cnt, recs);
        conv_merge_kernel<<<NBUCKET, 256, 0, stream>>>(feats, W, cnt, recs, out, stats);
        bn_kernel<<<512, 256, 0, stream>>>(out, stats, gamma, beta);
    } else {
        // --- legacy path (verified): atomic scatter + separate stats ---
        hipMemsetAsync(out, 0, (size_t)N_OUT * C * sizeof(float), stream);
        hipMemsetAsync(stats, 0, 2 * C * sizeof(float), stream);

        dim3 cgrid(MPAIR / 256, KOFF);
        conv_kernel<<<cgrid, 256, 0, stream>>>(feats, W, in_map, out_map, out);
        stats_kernel<<<256, 256, 0, stream>>>(out, stats);
        bn_kernel<<<512, 256, 0, stream>>>(out, stats, gamma, beta);
    }
}